// Round 3
// baseline (752.447 us; speedup 1.0000x reference)
//
#include <hip/hip_runtime.h>
#include <math.h>

#define Bn   16
#define Cn   256
#define Hn   128
#define Wn   128
#define HIDE 128
#define HW   (Hn * Wn)   // 16384

typedef __attribute__((ext_vector_type(4))) float f32x4;

// ---------------------------------------------------------------------------
// Kernel 1: per-(b,c) mean + fused per-batch gate MLP.
// One block per (b,c) plane (4096 blocks). After writing its mean, each block
// does __threadfence() + atomicAdd(counter[b]). The block that completes its
// batch (old == 255) acquires and computes the WHOLE gate row for batch b:
//   h = y_b @ w1.T; s = softmax(w2*h); t = relu(w3*(h*s + h@A2));
//   gate_b = sigmoid(t @ w4.T)
// Safe without cooperative launch: no co-residency assumption — the LAST
// finishing block does the work; atomicAdd is device-scope (G12/G16).
// ---------------------------------------------------------------------------
__global__ __launch_bounds__(256) void mean_gate_kernel(
    const float* __restrict__ x,
    const float* __restrict__ w1,
    const float* __restrict__ w2s,
    const float* __restrict__ w3s,
    const float* __restrict__ w4,
    const float* __restrict__ A2,
    float* __restrict__ y,
    float* __restrict__ gate,
    unsigned int* __restrict__ counters)
{
    const int bc  = blockIdx.x;
    const int b   = bc >> 8;          // 256 channels per batch
    const int tid = threadIdx.x;

    __shared__ float ls[4];
    __shared__ int   isLast;
    __shared__ float sy[Cn];
    __shared__ float sh[HIDE];
    __shared__ float st[HIDE];
    __shared__ float red[4];

    // ---- mean of this plane (cached loads: warms L3 with x for kernel 2) ----
    const f32x4* xp = (const f32x4*)(x + (size_t)bc * HW);
    float sum = 0.f;
#pragma unroll
    for (int i = 0; i < HW / 4 / 256; ++i) {   // 16 coalesced f32x4 loads
        f32x4 v = xp[tid + i * 256];
        sum += (v.x + v.y) + (v.z + v.w);
    }
    for (int off = 32; off; off >>= 1) sum += __shfl_down(sum, off, 64);
    if ((tid & 63) == 0) ls[tid >> 6] = sum;
    __syncthreads();
    if (tid == 0) {
        y[bc] = ((ls[0] + ls[1]) + (ls[2] + ls[3])) * (1.0f / (float)HW);
        __threadfence();                        // release y[bc] (device scope)
        unsigned old = atomicAdd(&counters[b], 1u);
        isLast = (old == Cn - 1);
    }
    __syncthreads();
    if (!isLast) return;                        // block-uniform exit

    // ---- last block of batch b: gate MLP (acquire, then compute) ----
    __threadfence();
    sy[tid] = y[b * Cn + tid];
    __syncthreads();

    const float w2 = w2s[0];
    const float w3 = w3s[0];

    // h[j] = sum_c y[c] * w1[j][c]
    if (tid < HIDE) {
        float acc = 0.f;
        const float* wr = w1 + tid * Cn;
#pragma unroll 4
        for (int c = 0; c < Cn; ++c) acc = fmaf(sy[c], wr[c], acc);
        sh[tid] = acc;
    }
    __syncthreads();

    // wave-parallel softmax max (2 full waves active)
    if (tid < HIDE) {
        float v = w2 * sh[tid];
        for (int off = 32; off; off >>= 1)
            v = fmaxf(v, __shfl_xor(v, off, 64));
        if ((tid & 63) == 0) red[tid >> 6] = v;
    }
    __syncthreads();
    const float m = fmaxf(red[0], red[1]);

    // wave-parallel softmax denom; keep own exp in register
    float e = 0.f;
    if (tid < HIDE) {
        e = expf(w2 * sh[tid] - m);
        float s = e;
        for (int off = 32; off; off >>= 1) s += __shfl_xor(s, off, 64);
        if ((tid & 63) == 0) red[2 + (tid >> 6)] = s;
    }
    __syncthreads();
    const float denom = red[2] + red[3];

    // t[j] = relu(w3 * (h[j]*s[j] + sum_k h[k]*A2[k][j]))
    if (tid < HIDE) {
        float sj  = e / denom;
        float acc = sh[tid] * sj;
        for (int kk = 0; kk < HIDE; ++kk)
            acc = fmaf(sh[kk], A2[kk * HIDE + tid], acc);
        float t = w3 * acc;
        st[tid] = t > 0.f ? t : 0.f;
    }
    __syncthreads();

    // gate[c] = sigmoid(sum_j t[j] * w4[c][j])
    {
        float acc = 0.f;
        const float* wr = w4 + tid * HIDE;
#pragma unroll 4
        for (int j = 0; j < HIDE; ++j) acc = fmaf(st[j], wr[j], acc);
        gate[b * Cn + tid] = 1.f / (1.f + expf(-acc));
    }
    // visibility of gate[] to kernel 2 is guaranteed by the kernel boundary
}

// ---------------------------------------------------------------------------
// Kernel 2: out[b,c,:,:] = x[b,c,:,:] * gate[b,c]. One block per plane.
// Cached loads for x (L3 hits, warmed by kernel 1); NON-TEMPORAL stores for
// out so the 256 MiB of streaming writes don't evict x from the LLC.
// ---------------------------------------------------------------------------
__global__ __launch_bounds__(256) void scale_kernel(const float* __restrict__ x,
                                                    const float* __restrict__ gate,
                                                    float* __restrict__ out) {
    const int bc  = blockIdx.x;
    const int tid = threadIdx.x;
    const float g = gate[bc];
    const f32x4* xp = (const f32x4*)(x   + (size_t)bc * HW);
    f32x4*       op = (f32x4*)      (out + (size_t)bc * HW);

#pragma unroll
    for (int i = 0; i < HW / 4 / 256; ++i) {   // 16 iters
        f32x4 v = xp[tid + i * 256];
        v *= g;
        __builtin_nontemporal_store(v, &op[tid + i * 256]);
    }
}

extern "C" void kernel_launch(void* const* d_in, const int* in_sizes, int n_in,
                              void* d_out, int out_size, void* d_ws, size_t ws_size,
                              hipStream_t stream) {
    const float* x  = (const float*)d_in[0];
    const float* w1 = (const float*)d_in[1];
    const float* w2 = (const float*)d_in[2];
    const float* w3 = (const float*)d_in[3];
    const float* w4 = (const float*)d_in[4];
    const float* A2 = (const float*)d_in[5];
    float* out = (float*)d_out;

    float*        y        = (float*)d_ws;            // B*C = 4096 floats
    float*        gate     = y + Bn * Cn;             // B*C = 4096 floats
    unsigned int* counters = (unsigned int*)(gate + Bn * Cn);  // 16 uints

    // zero the per-batch arrival counters (capture-safe async memset)
    hipMemsetAsync(counters, 0, Bn * sizeof(unsigned int), stream);

    mean_gate_kernel<<<Bn * Cn, 256, 0, stream>>>(x, w1, w2, w3, w4, A2,
                                                  y, gate, counters);
    scale_kernel   <<<Bn * Cn, 256, 0, stream>>>(x, gate, out);
}